// Round 2
// baseline (1728.325 us; speedup 1.0000x reference)
//
#include <hip/hip_runtime.h>
#include <hip/hip_bf16.h>

#define NN      100000
#define NE      1600000
#define RBF     128
#define DIM     64

// ---------- bf16 bit tricks ----------
__device__ __forceinline__ float lo_bf(unsigned int u) {
    union { unsigned int i; float f; } v; v.i = u << 16; return v.f;
}
__device__ __forceinline__ float hi_bf(unsigned int u) {
    union { unsigned int i; float f; } v; v.i = u & 0xffff0000u; return v.f;
}
__device__ __forceinline__ float us_bf(unsigned short u) {
    union { unsigned int i; float f; } v; v.i = ((unsigned int)u) << 16; return v.f;
}

// ---------- runtime dtype sniffer ----------
// flags[0] = 1 if float tensors are fp32 storage, 0 if bf16 storage
// flags[1] = 1 if edge_mask is int8/bool storage, 0 if int32 storage
// fp32 detection: low 16 bits of an fp32 word are random mantissa bits ->
// interpreted as bf16 the exponent field is ~uniform; bf16 N(0,1) data never
// has exponent >= 0x90 (|v| >= 2^17).
__global__ void sniff_kernel(const unsigned int* __restrict__ rbf_raw,
                             const unsigned int* __restrict__ mask_raw,
                             int* __restrict__ flags)
{
    const int lane = threadIdx.x & 63;
    int fh = 0, mh = 0;
    for (int i = lane; i < 256; i += 64) {
        const unsigned int u = rbf_raw[i];
        if (((u >> 7) & 0xffu) >= 0x90u) fh = 1;   // low-half bf16 exponent huge
        if (mask_raw[i] > 1u) mh = 1;              // int32 bool is only 0/1
    }
    const int fcnt = __popcll(__ballot(fh));
    const int mcnt = __popcll(__ballot(mh));
    if (lane == 0) {
        flags[0] = (fcnt >= 4) ? 1 : 0;
        flags[1] = (mcnt >= 4) ? 1 : 0;
    }
}

// ---------- fused edge kernel ----------
// One wave per kept edge; lane = output dim. W1/W2 columns in registers,
// wave-uniform rbf row (scalar loads), stage-2 broadcast via wave-private LDS,
// fp32 atomic scatter into d_ws accumulator.
template <bool FP32>
__global__ __launch_bounds__(256, 2)
void edge_kernel(const void* __restrict__ rbf_v,
                 const void* __restrict__ nn_v,
                 const int*  __restrict__ src,
                 const int*  __restrict__ dst,
                 const void* __restrict__ mask_v,
                 const void* __restrict__ W1_v,
                 const void* __restrict__ b1_v,
                 const void* __restrict__ W2_v,
                 const void* __restrict__ b2_v,
                 const int*  __restrict__ flags,
                 float*      __restrict__ acc)
{
    if ((flags[0] != 0) != FP32) return;   // uniform: wrong-dtype instance exits
    const int mask8 = flags[1];

    const int lane = threadIdx.x & 63;
    const int wib  = threadIdx.x >> 6;
    const int gw   = blockIdx.x * 4 + wib;
    const int nw   = gridDim.x * 4;

    // per-lane weight columns in registers
    float w1c[RBF];
    float w2c[DIM];
    float b1v, b2v;
    if constexpr (FP32) {
        const float* W1 = (const float*)W1_v;
        const float* W2 = (const float*)W2_v;
#pragma unroll
        for (int k = 0; k < RBF; ++k) w1c[k] = W1[k * DIM + lane];
#pragma unroll
        for (int j = 0; j < DIM; ++j) w2c[j] = W2[j * DIM + lane];
        b1v = ((const float*)b1_v)[lane];
        b2v = ((const float*)b2_v)[lane];
    } else {
        const unsigned short* W1 = (const unsigned short*)W1_v;
        const unsigned short* W2 = (const unsigned short*)W2_v;
#pragma unroll
        for (int k = 0; k < RBF; ++k) w1c[k] = us_bf(W1[k * DIM + lane]);
#pragma unroll
        for (int j = 0; j < DIM; ++j) w2c[j] = us_bf(W2[j * DIM + lane]);
        b1v = us_bf(((const unsigned short*)b1_v)[lane]);
        b2v = us_bf(((const unsigned short*)b2_v)[lane]);
    }

    __shared__ alignas(16) float sp_lds[4][DIM];
    float* myl = sp_lds[wib];

    for (int base = gw * 64; base < NE; base += nw * 64) {
        const int e_l = base + lane;
        int m_l;
        if (mask8) m_l = ((const unsigned char*)mask_v)[e_l];
        else       m_l = ((const int*)mask_v)[e_l];
        const int s_l = src[e_l];
        const int d_l = dst[e_l];
        unsigned long long bal = __ballot(m_l != 0);

        while (bal) {
            const int l = __ffsll((unsigned long long)bal) - 1;
            bal &= bal - 1;
            const int ee = __builtin_amdgcn_readfirstlane(base + l);
            const int s  = __shfl(s_l, l);
            const int d  = __shfl(d_l, l);

            // ---- stage 1: x[lane] = b1 + rbf[ee,:] . W1[:,lane] ----
            float a0 = b1v, a1 = 0.f, a2 = 0.f, a3 = 0.f;
            if constexpr (FP32) {
                const float4* r = (const float4*)((const float*)rbf_v + (size_t)ee * RBF);
#pragma unroll
                for (int q = 0; q < RBF / 4; q += 4) {
                    const float4 v0 = r[q + 0], v1 = r[q + 1];
                    const float4 v2 = r[q + 2], v3 = r[q + 3];
                    a0 += v0.x*w1c[4*q+ 0] + v0.y*w1c[4*q+ 1] + v0.z*w1c[4*q+ 2] + v0.w*w1c[4*q+ 3];
                    a1 += v1.x*w1c[4*q+ 4] + v1.y*w1c[4*q+ 5] + v1.z*w1c[4*q+ 6] + v1.w*w1c[4*q+ 7];
                    a2 += v2.x*w1c[4*q+ 8] + v2.y*w1c[4*q+ 9] + v2.z*w1c[4*q+10] + v2.w*w1c[4*q+11];
                    a3 += v3.x*w1c[4*q+12] + v3.y*w1c[4*q+13] + v3.z*w1c[4*q+14] + v3.w*w1c[4*q+15];
                }
            } else {
                const unsigned int* r = (const unsigned int*)rbf_v + (size_t)ee * (RBF / 2);
#pragma unroll
                for (int k2 = 0; k2 < RBF / 2; k2 += 4) {
                    const unsigned int u0 = r[k2 + 0], u1 = r[k2 + 1];
                    const unsigned int u2 = r[k2 + 2], u3 = r[k2 + 3];
                    a0 += lo_bf(u0) * w1c[2*k2 + 0] + hi_bf(u0) * w1c[2*k2 + 1];
                    a1 += lo_bf(u1) * w1c[2*k2 + 2] + hi_bf(u1) * w1c[2*k2 + 3];
                    a2 += lo_bf(u2) * w1c[2*k2 + 4] + hi_bf(u2) * w1c[2*k2 + 5];
                    a3 += lo_bf(u3) * w1c[2*k2 + 6] + hi_bf(u3) * w1c[2*k2 + 7];
                }
            }
            const float x = (a0 + a1) + (a2 + a3);

            // softplus(beta=0.5, threshold=14): exact identity when 0.5x > 14
            const float bx = 0.5f * x;
            float sp;
            if (bx > 14.0f) sp = x;
            else sp = 2.0f * (fmaxf(bx, 0.0f) + log1pf(__expf(-fabsf(bx))));

            // ---- stage 2: h[lane] = b2 + sp[:] . W2[:,lane] ----
            myl[lane] = sp;
            __builtin_amdgcn_wave_barrier();
            const float4* spv = (const float4*)myl;
            float h0 = b2v, h1 = 0.f, h2 = 0.f, h3 = 0.f;
#pragma unroll
            for (int j4 = 0; j4 < DIM / 4; j4 += 4) {
                const float4 v0 = spv[j4 + 0], v1 = spv[j4 + 1];
                const float4 v2 = spv[j4 + 2], v3 = spv[j4 + 3];
                h0 += v0.x*w2c[4*j4+ 0] + v0.y*w2c[4*j4+ 1] + v0.z*w2c[4*j4+ 2] + v0.w*w2c[4*j4+ 3];
                h1 += v1.x*w2c[4*j4+ 4] + v1.y*w2c[4*j4+ 5] + v1.z*w2c[4*j4+ 6] + v1.w*w2c[4*j4+ 7];
                h2 += v2.x*w2c[4*j4+ 8] + v2.y*w2c[4*j4+ 9] + v2.z*w2c[4*j4+10] + v2.w*w2c[4*j4+11];
                h3 += v3.x*w2c[4*j4+12] + v3.y*w2c[4*j4+13] + v3.z*w2c[4*j4+14] + v3.w*w2c[4*j4+15];
            }
            const float h = (h0 + h1) + (h2 + h3);
            __builtin_amdgcn_wave_barrier();

            // ---- msg + scatter ----
            float nnv;
            if constexpr (FP32) nnv = ((const float*)nn_v)[(size_t)s * DIM + lane];
            else                nnv = us_bf(((const unsigned short*)nn_v)[(size_t)s * DIM + lane]);
            atomicAdd(&acc[(size_t)d * DIM + lane], nnv * h);
        }
    }
}

// output dtype follows float-storage flag: fp32 storage -> fp32 out, else bf16
__global__ void finalize_kernel(const float* __restrict__ acc,
                                void* __restrict__ out,
                                const int* __restrict__ flags, int n)
{
    const int i = blockIdx.x * blockDim.x + threadIdx.x;
    if (i < n) {
        const float v = acc[i];
        if (flags[0]) ((float*)out)[i] = v;
        else          ((__hip_bfloat16*)out)[i] = __float2bfloat16(v);
    }
}

extern "C" void kernel_launch(void* const* d_in, const int* in_sizes, int n_in,
                              void* d_out, int out_size, void* d_ws, size_t ws_size,
                              hipStream_t stream)
{
    const void* rbf  = d_in[0];
    const void* nn   = d_in[1];
    const int*  src  = (const int*)d_in[2];
    const int*  dst  = (const int*)d_in[3];
    const void* mask = d_in[4];
    const void* W1   = d_in[5];
    const void* b1   = d_in[6];
    const void* W2   = d_in[7];
    const void* b2   = d_in[8];

    int*   flags = (int*)d_ws;                 // flags[0..1]
    float* acc   = (float*)d_ws + 64;          // 256B offset; NN*DIM fp32 = 25.6 MB

    hipMemsetAsync(acc, 0, (size_t)NN * DIM * sizeof(float), stream);
    sniff_kernel<<<1, 64, 0, stream>>>((const unsigned int*)rbf,
                                       (const unsigned int*)mask, flags);
    edge_kernel<true ><<<512, 256, 0, stream>>>(rbf, nn, src, dst, mask,
                                                W1, b1, W2, b2, flags, acc);
    edge_kernel<false><<<512, 256, 0, stream>>>(rbf, nn, src, dst, mask,
                                                W1, b1, W2, b2, flags, acc);
    finalize_kernel<<<((NN * DIM) + 255) / 256, 256, 0, stream>>>(
        acc, d_out, flags, NN * DIM);
}